// Round 13
// baseline (221.616 us; speedup 1.0000x reference)
//
#include <hip/hip_runtime.h>
#include <math.h>

#define N 512
#define NN (N * N)
#define C 16
#define K 262144
#define LOG2N 9

// skewed LDS addressing (float4-element units): +1 every 16 elements.
#define SK(e) ((e) + ((e) >> 4))
#define LROW 545

// clang ext-vector types for nontemporal builtins (HIP float4 is a struct)
typedef __attribute__((ext_vector_type(4))) float f4v;
typedef __attribute__((ext_vector_type(2))) float f2v;

__device__ __forceinline__ f4v nt_load4(const void* p) {
    return __builtin_nontemporal_load((const f4v*)p);
}
__device__ __forceinline__ void nt_store4(void* p, f4v v) {
    __builtin_nontemporal_store(v, (f4v*)p);
}
__device__ __forceinline__ void nt_store2(void* p, float x, float y) {
    f2v v; v.x = x; v.y = y;
    __builtin_nontemporal_store(v, (f2v*)p);
}

__device__ __forceinline__ float4 f4add(float4 a, float4 b) {
    return make_float4(a.x + b.x, a.y + b.y, a.z + b.z, a.w + b.w);
}
__device__ __forceinline__ float4 f4sub(float4 a, float4 b) {
    return make_float4(a.x - b.x, a.y - b.y, a.z - b.z, a.w - b.w);
}
__device__ __forceinline__ float4 cmulf4(float4 a, float c, float s) {
    return make_float4(c * a.x - s * a.y, c * a.y + s * a.x,
                       c * a.z - s * a.w, c * a.w + s * a.z);
}
__device__ __forceinline__ float4 cmuli(float4 a) {   // multiply by i
    return make_float4(-a.y, a.x, -a.w, a.z);
}

// ============ radix-8 butterfly (verified rounds 8-12) ============
__device__ __forceinline__ void rad8(float4* stripe, int p0, int h, float th1) {
    float s1, c1, s2, c2, s3, c3;
    __sincosf(th1, &s1, &c1);
    __sincosf(0.5f * th1, &s2, &c2);
    __sincosf(0.25f * th1, &s3, &c3);
    const float r2 = 0.70710678118654752f;
    float c3r = r2 * (c3 - s3), s3r = r2 * (c3 + s3);   // W3 * e^{i pi/4}
    float4 x0 = stripe[SK(p0)];
    float4 x1 = stripe[SK(p0 + h)];
    float4 x2 = stripe[SK(p0 + 2 * h)];
    float4 x3 = stripe[SK(p0 + 3 * h)];
    float4 x4 = stripe[SK(p0 + 4 * h)];
    float4 x5 = stripe[SK(p0 + 5 * h)];
    float4 x6 = stripe[SK(p0 + 6 * h)];
    float4 x7 = stripe[SK(p0 + 7 * h)];
    float4 t;
    t = cmulf4(x1, c1, s1); float4 y0 = f4add(x0, t), y1 = f4sub(x0, t);
    t = cmulf4(x3, c1, s1); float4 y2 = f4add(x2, t), y3 = f4sub(x2, t);
    t = cmulf4(x5, c1, s1); float4 y4 = f4add(x4, t), y5 = f4sub(x4, t);
    t = cmulf4(x7, c1, s1); float4 y6 = f4add(x6, t), y7 = f4sub(x6, t);
    t = cmulf4(y2, c2, s2);        float4 z0 = f4add(y0, t), z2 = f4sub(y0, t);
    t = cmuli(cmulf4(y3, c2, s2)); float4 z1 = f4add(y1, t), z3 = f4sub(y1, t);
    t = cmulf4(y6, c2, s2);        float4 z4 = f4add(y4, t), z6 = f4sub(y4, t);
    t = cmuli(cmulf4(y7, c2, s2)); float4 z5 = f4add(y5, t), z7 = f4sub(y5, t);
    float4 w0 = cmulf4(z4, c3, s3);
    float4 w1 = cmulf4(z5, c3r, s3r);
    float4 w2 = cmuli(cmulf4(z6, c3, s3));
    float4 w3 = cmuli(cmulf4(z7, c3r, s3r));
    stripe[SK(p0)]         = f4add(z0, w0);
    stripe[SK(p0 + 4 * h)] = f4sub(z0, w0);
    stripe[SK(p0 + h)]     = f4add(z1, w1);
    stripe[SK(p0 + 5 * h)] = f4sub(z1, w1);
    stripe[SK(p0 + 2 * h)] = f4add(z2, w2);
    stripe[SK(p0 + 6 * h)] = f4sub(z2, w2);
    stripe[SK(p0 + 3 * h)] = f4add(z3, w3);
    stripe[SK(p0 + 7 * h)] = f4sub(z3, w3);
}

// 512-pt FFT, input bit-reversed, output natural: 3 radix-8 stage-triples,
// wave-local (stage ordering via s_waitcnt lgkmcnt(0), no __syncthreads).
__device__ __forceinline__ void fft512_wave(float4* stripe, int l) {
    rad8(stripe, l * 8, 1, 0.0f);                                   // stages 1-3
    asm volatile("s_waitcnt lgkmcnt(0)" ::: "memory");
    rad8(stripe, (l >> 3) * 64 + (l & 7), 8,                        // stages 4-6
         6.283185307179586f * (float)(l & 7) * (1.0f / 16.0f));
    asm volatile("s_waitcnt lgkmcnt(0)" ::: "memory");
    rad8(stripe, l, 64,                                             // stages 7-9
         6.283185307179586f * (float)l * (1.0f / 128.0f));
    asm volatile("s_waitcnt lgkmcnt(0)" ::: "memory");
}

// ============ phase 1: pure histogram (2 points/thread, float4 loads) ============
__global__ __launch_bounds__(256) void prep_hist_kernel(const float4* __restrict__ traj2,
                                                        int* __restrict__ count) {
    int k2 = blockIdx.x * 256 + threadIdx.x;
    float4 t2 = traj2[k2];
    int iy0 = __float2int_rn((t2.x + 0.5f) * (float)N) & (N - 1);
    int ix0 = __float2int_rn((t2.y + 0.5f) * (float)N) & (N - 1);
    int iy1 = __float2int_rn((t2.z + 0.5f) * (float)N) & (N - 1);
    int ix1 = __float2int_rn((t2.w + 0.5f) * (float)N) & (N - 1);
    atomicAdd(&count[iy0 * N + ix0], 1);
    atomicAdd(&count[iy1 * N + ix1], 1);
}

// ============ single-kernel scan: offs/cursor from count (round-12 proven) ============
__global__ __launch_bounds__(256) void scan_kernel(const int* __restrict__ count,
                                                   int* __restrict__ offs,
                                                   int* __restrict__ cursor) {
    __shared__ int sd[256];
    int t = threadIdx.x;
    int b = blockIdx.x;
    const int4* c4all = (const int4*)count;

    int4 c4 = c4all[b * 256 + t];
    int s = c4.x + c4.y + c4.z + c4.w;
    sd[t] = s;
    __syncthreads();
    for (int d = 1; d < 256; d <<= 1) {
        int tmp = (t >= d) ? sd[t - d] : 0;
        __syncthreads();
        sd[t] += tmp;
        __syncthreads();
    }
    int epre = sd[t] - s;

    int lim = b * 256;
    int p0 = 0, p1 = 0, p2 = 0, p3 = 0;
    int i = t;
    for (; i + 768 < lim; i += 1024) {
        int4 a = c4all[i], bb = c4all[i + 256], cc = c4all[i + 512], dd = c4all[i + 768];
        p0 += a.x + a.y + a.z + a.w;
        p1 += bb.x + bb.y + bb.z + bb.w;
        p2 += cc.x + cc.y + cc.z + cc.w;
        p3 += dd.x + dd.y + dd.z + dd.w;
    }
    for (; i < lim; i += 256) {
        int4 a = c4all[i];
        p0 += a.x + a.y + a.z + a.w;
    }
    __syncthreads();
    sd[t] = p0 + p1 + p2 + p3;
    __syncthreads();
    for (int d = 128; d > 0; d >>= 1) {
        if (t < d) sd[t] += sd[t + d];
        __syncthreads();
    }
    int base = sd[0] + epre;

    int4 o;
    o.x = base;
    o.y = base + c4.x;
    o.z = base + c4.x + c4.y;
    o.w = base + c4.x + c4.y + c4.z;
    ((int4*)offs)[b * 256 + t] = o;
    ((int4*)cursor)[b * 256 + t] = o;
    if (b == 0 && t == 0) offs[NN] = K;
}

// ============ payload build: transpose x to sorted point order ============
// pay is written once and read once (build8) -> NONTEMPORAL stores keep the
// 32-MB stream from evicting x/grid/csm out of L2.
__global__ __launch_bounds__(256) void payload_kernel(const float* __restrict__ xr,
                                                      const float* __restrict__ xi,
                                                      const float2* __restrict__ traj,
                                                      const float* __restrict__ dcf,
                                                      int* __restrict__ cursor,
                                                      float2* __restrict__ pay) {
    __shared__ float tR[256][17];   // [point][channel], +1 pad -> conflict-free
    __shared__ float tI[256][17];
    __shared__ int   sp[256];
    __shared__ float sw[256];
    int t = threadIdx.x;
    int k0 = blockIdx.x * 256;
#pragma unroll
    for (int c = 0; c < C; ++c) {
        tR[t][c] = xr[(size_t)c * K + k0 + t];   // coalesced 1-KB reads
        tI[t][c] = xi[(size_t)c * K + k0 + t];
    }
    float2 tr = traj[k0 + t];
    int iy = __float2int_rn((tr.x + 0.5f) * (float)N) & (N - 1);
    int ix = __float2int_rn((tr.y + 0.5f) * (float)N) & (N - 1);
    int cl = iy * N + ix;
    sp[t] = atomicAdd(&cursor[cl], 1);           // unique sorted slot
    sw[t] = dcf[k0 + t] * (((iy + ix) & 1) ? -1.0f : 1.0f);
    __syncthreads();
    int sg = t >> 4, l = t & 15;                 // 16 subgroups of 16 lanes
    for (int j = sg; j < 256; j += 16) {
        int pp = sp[j];
        float ww = sw[j];
        // 16 lanes write one contiguous 128-B chunk (full HBM granule)
        nt_store2(&pay[(size_t)pp * 16 + l], tR[j][l] * ww, tI[j][l] * ww);
    }
}

// ============ grid-build + row FFT: one block per row, all 16 channels ============
// (round-12 proven) + NONTEMPORAL pay reads (read-once stream).
__global__ __launch_bounds__(512) void build8_kernel(const int* __restrict__ offs,
                                                     const float4* __restrict__ pay4,
                                                     float2* __restrict__ grid) {
    __shared__ float4 lds[8][LROW];   // 69.8 KB -> 2 blocks/CU
    int r = blockIdx.x;
    int t = threadIdx.x;
    int w = t >> 6;                   // wave = channel quad q
    int l = t & 63;
    const int* ro = offs + r * N;

    int sv[8], ev[8];
#pragma unroll
    for (int it = 0; it < 8; ++it) {
        int col = l + (it << 6);
        sv[it] = ro[col];
        ev[it] = ro[col + 1];         // col=511,r=511 reads offs[NN]=K
    }
    // prefetch first TWO points per cell (covers 92% of cells), all in flight
    f4v vv[8], vv2[8];
#pragma unroll
    for (int it = 0; it < 8; ++it) {
        vv[it] = (f4v)0.f;
        if (sv[it] < ev[it]) vv[it] = nt_load4(&pay4[(size_t)sv[it] * 8 + w]);
    }
#pragma unroll
    for (int it = 0; it < 8; ++it) {
        vv2[it] = (f4v)0.f;
        if (sv[it] + 1 < ev[it]) vv2[it] = nt_load4(&pay4[(size_t)(sv[it] + 1) * 8 + w]);
    }
#pragma unroll
    for (int it = 0; it < 8; ++it) {
        f4v accv = vv[it] + vv2[it];
        float4 acc = make_float4(accv.x, accv.y, accv.z, accv.w);
        for (int p = sv[it] + 2; p < ev[it]; ++p) {   // rare tail (8% of cells)
            f4v v2 = nt_load4(&pay4[(size_t)p * 8 + w]);
            acc.x += v2.x; acc.y += v2.y; acc.z += v2.z; acc.w += v2.w;
        }
        int col = l + (it << 6);
        int bc = (int)(__brev((unsigned)col) >> (32 - LOG2N));   // bit-reversed col
        lds[w][SK(bc)] = acc;
    }
    asm volatile("s_waitcnt lgkmcnt(0)" ::: "memory");

    fft512_wave(&lds[w][0], l);

    // ---- store this wave's 2 channels, coalesced (re-read by colfft: cached) ----
    int c0 = w * 2;
    float2* g0 = grid + (size_t)c0 * NN + (size_t)r * N;
    float2* g1 = grid + (size_t)(c0 + 1) * NN + (size_t)r * N;
    for (int i = l; i < N; i += 64) {
        float4 v = lds[w][SK(i)];
        g0[i] = make_float2(v.x, v.y);
        g1[i] = make_float2(v.z, v.w);
    }
}

// ============ column FFT: full-granule load/store phases (round-12) ============
__global__ __launch_bounds__(512) void colfft_kernel(float2* __restrict__ grid) {
    __shared__ float4 lds[8][LROW];   // 69.8 KB
    int blk = blockIdx.x;             // c * 32 + cg
    int c = blk >> 5;
    int cg = blk & 31;
    int t = threadIdx.x;
    int w = t >> 6;
    int l = t & 63;
    float2* gb = grid + (size_t)c * NN + cg * 16;
    int cp = t & 7;                   // column pair 0..7 within the 16-col slab
    int r0 = t >> 3;                  // base row 0..63

    // ---- load: 8 lanes per row = full 128-B granule; bit-reversed scatter ----
#pragma unroll
    for (int j = 0; j < 8; ++j) {
        int row = r0 + (j << 6);
        float4 v = ((const float4*)(gb + (size_t)row * N))[cp];
        int br = (int)(__brev((unsigned)row) >> (32 - LOG2N));
        lds[cp][SK(br)] = v;
    }
    __syncthreads();

    fft512_wave(&lds[w][0], l);
    __syncthreads();

    // ---- store: natural order, full granules (re-read by combine: cached) ----
#pragma unroll
    for (int j = 0; j < 8; ++j) {
        int row = r0 + (j << 6);
        ((float4*)(gb + (size_t)row * N))[cp] = lds[cp][SK(row)];
    }
}

// ============ combine: 4 pixels/thread; nt grid loads (dead after), nt out stores ============
__global__ __launch_bounds__(256) void combine_kernel(const float* __restrict__ csr,
                                                      const float* __restrict__ csi,
                                                      const float2* __restrict__ grid,
                                                      float* __restrict__ out) {
    int p4 = blockIdx.x * 256 + threadIdx.x;     // pixel-quad index (NN/4 total)
    int pix = p4 * 4;
    int ny = pix >> LOG2N, nx = pix & (N - 1);
    float ar0 = 0.f, ai0 = 0.f, ar1 = 0.f, ai1 = 0.f;
    float ar2 = 0.f, ai2 = 0.f, ar3 = 0.f, ai3 = 0.f;
#pragma unroll
    for (int c = 0; c < C; ++c) {
        const float4* gc = (const float4*)(grid + (size_t)c * NN);
        f4v uv01 = nt_load4(&gc[p4 * 2]);        // pixels 0,1 (2 complex)
        f4v uv23 = nt_load4(&gc[p4 * 2 + 1]);    // pixels 2,3
        f4v a = nt_load4(&((const float4*)(csr + (size_t)c * NN))[p4]);
        f4v b = nt_load4(&((const float4*)(csi + (size_t)c * NN))[p4]);
        ar0 += a.x * uv01.x + b.x * uv01.y;  ai0 += a.x * uv01.y - b.x * uv01.x;
        ar1 += a.y * uv01.z + b.y * uv01.w;  ai1 += a.y * uv01.w - b.y * uv01.z;
        ar2 += a.z * uv23.x + b.z * uv23.y;  ai2 += a.z * uv23.y - b.z * uv23.x;
        ar3 += a.w * uv23.z + b.w * uv23.w;  ai3 += a.w * uv23.w - b.w * uv23.z;
    }
    float s0 = ((ny + nx) & 1) ? -1.f : 1.f;     // fftshift sign; alternates per col
    f4v vre, vim;
    vre.x = s0 * ar0; vre.y = -s0 * ar1; vre.z = s0 * ar2; vre.w = -s0 * ar3;
    vim.x = s0 * ai0; vim.y = -s0 * ai1; vim.z = s0 * ai2; vim.w = -s0 * ai3;
    nt_store4(&((float4*)out)[p4], vre);
    nt_store4(&((float4*)(out + NN))[p4], vim);
}

extern "C" void kernel_launch(void* const* d_in, const int* in_sizes, int n_in,
                              void* d_out, int out_size, void* d_ws, size_t ws_size,
                              hipStream_t stream) {
    const float* x_real   = (const float*)d_in[0];
    const float* x_imag   = (const float*)d_in[1];
    const float* csm_real = (const float*)d_in[2];
    const float* csm_imag = (const float*)d_in[3];
    const float2* traj    = (const float2*)d_in[4];
    const float* dcf      = (const float*)d_in[5];
    float* out = (float*)d_out;

    char* ws = (char*)d_ws;
    size_t o = 0;
    float* grid  = (float*)(ws + o); o += (size_t)C * NN * 2 * sizeof(float);  // 32 MB
    int*   count = (int*)(ws + o);   o += (size_t)NN * sizeof(int);            // 1 MB
    int*   offs  = (int*)(ws + o);   o += ((size_t)NN + 4) * sizeof(int);      // 1 MB (+pad)
    int*   cursor= (int*)(ws + o);   o += (size_t)NN * sizeof(int);            // 1 MB
    float2* pay  = (float2*)(ws + o); o += (size_t)K * 16 * sizeof(float2);    // 32 MB

    (void)hipMemsetAsync(count, 0, (size_t)NN * sizeof(int), stream);

    prep_hist_kernel<<<K / 512, 256, 0, stream>>>((const float4*)traj, count);
    scan_kernel<<<256, 256, 0, stream>>>(count, offs, cursor);
    payload_kernel<<<K / 256, 256, 0, stream>>>(x_real, x_imag, traj, dcf, cursor, pay);
    build8_kernel<<<N, 512, 0, stream>>>(offs, (const float4*)pay, (float2*)grid);
    colfft_kernel<<<C * 32, 512, 0, stream>>>((float2*)grid);
    combine_kernel<<<NN / 1024, 256, 0, stream>>>(csm_real, csm_imag, (float2*)grid, out);
}

// Round 14
// 192.901 us; speedup vs baseline: 1.1489x; 1.1489x over previous
//
#include <hip/hip_runtime.h>
#include <math.h>

#define N 512
#define NN (N * N)
#define C 16
#define K 262144
#define LOG2N 9

// skewed LDS addressing (float4-element units): +1 every 16 elements.
// LROW=545 -> the 8 wave stripes start on banks 0,4,8,...,28: cross-stripe
// accesses in colfft's granule-remap phases spread across all banks.
#define SK(e) ((e) + ((e) >> 4))
#define LROW 545

__device__ __forceinline__ float4 f4add(float4 a, float4 b) {
    return make_float4(a.x + b.x, a.y + b.y, a.z + b.z, a.w + b.w);
}
__device__ __forceinline__ float4 f4sub(float4 a, float4 b) {
    return make_float4(a.x - b.x, a.y - b.y, a.z - b.z, a.w - b.w);
}
__device__ __forceinline__ float4 cmulf4(float4 a, float c, float s) {
    return make_float4(c * a.x - s * a.y, c * a.y + s * a.x,
                       c * a.z - s * a.w, c * a.w + s * a.z);
}
__device__ __forceinline__ float4 cmuli(float4 a) {   // multiply by i
    return make_float4(-a.y, a.x, -a.w, a.z);
}

// ============ radix-8 butterfly (verified rounds 8-13) ============
__device__ __forceinline__ void rad8(float4* stripe, int p0, int h, float th1) {
    float s1, c1, s2, c2, s3, c3;
    __sincosf(th1, &s1, &c1);
    __sincosf(0.5f * th1, &s2, &c2);
    __sincosf(0.25f * th1, &s3, &c3);
    const float r2 = 0.70710678118654752f;
    float c3r = r2 * (c3 - s3), s3r = r2 * (c3 + s3);   // W3 * e^{i pi/4}
    float4 x0 = stripe[SK(p0)];
    float4 x1 = stripe[SK(p0 + h)];
    float4 x2 = stripe[SK(p0 + 2 * h)];
    float4 x3 = stripe[SK(p0 + 3 * h)];
    float4 x4 = stripe[SK(p0 + 4 * h)];
    float4 x5 = stripe[SK(p0 + 5 * h)];
    float4 x6 = stripe[SK(p0 + 6 * h)];
    float4 x7 = stripe[SK(p0 + 7 * h)];
    float4 t;
    t = cmulf4(x1, c1, s1); float4 y0 = f4add(x0, t), y1 = f4sub(x0, t);
    t = cmulf4(x3, c1, s1); float4 y2 = f4add(x2, t), y3 = f4sub(x2, t);
    t = cmulf4(x5, c1, s1); float4 y4 = f4add(x4, t), y5 = f4sub(x4, t);
    t = cmulf4(x7, c1, s1); float4 y6 = f4add(x6, t), y7 = f4sub(x6, t);
    t = cmulf4(y2, c2, s2);        float4 z0 = f4add(y0, t), z2 = f4sub(y0, t);
    t = cmuli(cmulf4(y3, c2, s2)); float4 z1 = f4add(y1, t), z3 = f4sub(y1, t);
    t = cmulf4(y6, c2, s2);        float4 z4 = f4add(y4, t), z6 = f4sub(y4, t);
    t = cmuli(cmulf4(y7, c2, s2)); float4 z5 = f4add(y5, t), z7 = f4sub(y5, t);
    float4 w0 = cmulf4(z4, c3, s3);
    float4 w1 = cmulf4(z5, c3r, s3r);
    float4 w2 = cmuli(cmulf4(z6, c3, s3));
    float4 w3 = cmuli(cmulf4(z7, c3r, s3r));
    stripe[SK(p0)]         = f4add(z0, w0);
    stripe[SK(p0 + 4 * h)] = f4sub(z0, w0);
    stripe[SK(p0 + h)]     = f4add(z1, w1);
    stripe[SK(p0 + 5 * h)] = f4sub(z1, w1);
    stripe[SK(p0 + 2 * h)] = f4add(z2, w2);
    stripe[SK(p0 + 6 * h)] = f4sub(z2, w2);
    stripe[SK(p0 + 3 * h)] = f4add(z3, w3);
    stripe[SK(p0 + 7 * h)] = f4sub(z3, w3);
}

// 512-pt FFT, input bit-reversed, output natural: 3 radix-8 stage-triples,
// wave-local (stage ordering via s_waitcnt lgkmcnt(0), no __syncthreads).
__device__ __forceinline__ void fft512_wave(float4* stripe, int l) {
    rad8(stripe, l * 8, 1, 0.0f);                                   // stages 1-3
    asm volatile("s_waitcnt lgkmcnt(0)" ::: "memory");
    rad8(stripe, (l >> 3) * 64 + (l & 7), 8,                        // stages 4-6
         6.283185307179586f * (float)(l & 7) * (1.0f / 16.0f));
    asm volatile("s_waitcnt lgkmcnt(0)" ::: "memory");
    rad8(stripe, l, 64,                                             // stages 7-9
         6.283185307179586f * (float)l * (1.0f / 128.0f));
    asm volatile("s_waitcnt lgkmcnt(0)" ::: "memory");
}

// ============ phase 1: pure histogram (2 points/thread, float4 loads) ============
__global__ __launch_bounds__(256) void prep_hist_kernel(const float4* __restrict__ traj2,
                                                        int* __restrict__ count) {
    int k2 = blockIdx.x * 256 + threadIdx.x;
    float4 t2 = traj2[k2];
    int iy0 = __float2int_rn((t2.x + 0.5f) * (float)N) & (N - 1);
    int ix0 = __float2int_rn((t2.y + 0.5f) * (float)N) & (N - 1);
    int iy1 = __float2int_rn((t2.z + 0.5f) * (float)N) & (N - 1);
    int ix1 = __float2int_rn((t2.w + 0.5f) * (float)N) & (N - 1);
    atomicAdd(&count[iy0 * N + ix0], 1);
    atomicAdd(&count[iy1 * N + ix1], 1);
}

// ============ single-kernel scan: offs/cursor from count (round-12 proven) ============
__global__ __launch_bounds__(256) void scan_kernel(const int* __restrict__ count,
                                                   int* __restrict__ offs,
                                                   int* __restrict__ cursor) {
    __shared__ int sd[256];
    int t = threadIdx.x;
    int b = blockIdx.x;
    const int4* c4all = (const int4*)count;

    // own chunk + local inclusive scan
    int4 c4 = c4all[b * 256 + t];
    int s = c4.x + c4.y + c4.z + c4.w;
    sd[t] = s;
    __syncthreads();
    for (int d = 1; d < 256; d <<= 1) {
        int tmp = (t >= d) ? sd[t - d] : 0;
        __syncthreads();
        sd[t] += tmp;
        __syncthreads();
    }
    int epre = sd[t] - s;            // exclusive prefix within block

    // global exclusive base: reduce count[0 .. b*256 int4), 4-way ILP
    int lim = b * 256;
    int p0 = 0, p1 = 0, p2 = 0, p3 = 0;
    int i = t;
    for (; i + 768 < lim; i += 1024) {
        int4 a = c4all[i], bb = c4all[i + 256], cc = c4all[i + 512], dd = c4all[i + 768];
        p0 += a.x + a.y + a.z + a.w;
        p1 += bb.x + bb.y + bb.z + bb.w;
        p2 += cc.x + cc.y + cc.z + cc.w;
        p3 += dd.x + dd.y + dd.z + dd.w;
    }
    for (; i < lim; i += 256) {
        int4 a = c4all[i];
        p0 += a.x + a.y + a.z + a.w;
    }
    __syncthreads();
    sd[t] = p0 + p1 + p2 + p3;
    __syncthreads();
    for (int d = 128; d > 0; d >>= 1) {
        if (t < d) sd[t] += sd[t + d];
        __syncthreads();
    }
    int base = sd[0] + epre;

    int4 o;
    o.x = base;
    o.y = base + c4.x;
    o.z = base + c4.x + c4.y;
    o.w = base + c4.x + c4.y + c4.z;
    ((int4*)offs)[b * 256 + t] = o;
    ((int4*)cursor)[b * 256 + t] = o;
    if (b == 0 && t == 0) offs[NN] = K;
}

// ============ payload build: transpose x to sorted point order ============
__global__ __launch_bounds__(256) void payload_kernel(const float* __restrict__ xr,
                                                      const float* __restrict__ xi,
                                                      const float2* __restrict__ traj,
                                                      const float* __restrict__ dcf,
                                                      int* __restrict__ cursor,
                                                      float2* __restrict__ pay) {
    __shared__ float tR[256][17];   // [point][channel], +1 pad -> conflict-free
    __shared__ float tI[256][17];
    __shared__ int   sp[256];
    __shared__ float sw[256];
    int t = threadIdx.x;
    int k0 = blockIdx.x * 256;
#pragma unroll
    for (int c = 0; c < C; ++c) {
        tR[t][c] = xr[(size_t)c * K + k0 + t];   // coalesced 1-KB reads
        tI[t][c] = xi[(size_t)c * K + k0 + t];
    }
    float2 tr = traj[k0 + t];
    int iy = __float2int_rn((tr.x + 0.5f) * (float)N) & (N - 1);
    int ix = __float2int_rn((tr.y + 0.5f) * (float)N) & (N - 1);
    int cl = iy * N + ix;
    sp[t] = atomicAdd(&cursor[cl], 1);           // unique sorted slot
    sw[t] = dcf[k0 + t] * (((iy + ix) & 1) ? -1.0f : 1.0f);
    __syncthreads();
    int sg = t >> 4, l = t & 15;                 // 16 subgroups of 16 lanes
    for (int j = sg; j < 256; j += 16) {
        int pp = sp[j];
        float ww = sw[j];
        // 16 lanes write one contiguous 128-B chunk (full HBM granule)
        pay[(size_t)pp * 16 + l] = make_float2(tR[j][l] * ww, tI[j][l] * ww);
    }
}

// ============ grid-build + row FFT: one block per row, all 16 channels ============
// 512 threads = 8 waves; wave w owns channels {2w,2w+1} (float4 quarter w of
// each 128-B pay chunk) -> every pay granule is consumed inside ONE block/XCD.
// CACHED pay loads (8 waves share each 128-B line: L1/L2 reuse is essential --
// round-13's nontemporal loads broke exactly this, +25 us).
__global__ __launch_bounds__(512) void build8_kernel(const int* __restrict__ offs,
                                                     const float4* __restrict__ pay4,
                                                     float2* __restrict__ grid) {
    __shared__ float4 lds[8][LROW];   // 69.8 KB -> 2 blocks/CU
    int r = blockIdx.x;
    int t = threadIdx.x;
    int w = t >> 6;                   // wave = channel quad
    int l = t & 63;
    const int* ro = offs + r * N;

    int sv[8], ev[8];
#pragma unroll
    for (int it = 0; it < 8; ++it) {
        int col = l + (it << 6);
        sv[it] = ro[col];
        ev[it] = ro[col + 1];         // col=511,r=511 reads offs[NN]=K
    }
    // prefetch first TWO points per cell (covers 92% of cells), all in flight
    float4 vv[8], vv2[8];
#pragma unroll
    for (int it = 0; it < 8; ++it) {
        vv[it] = make_float4(0.f, 0.f, 0.f, 0.f);
        if (sv[it] < ev[it]) vv[it] = pay4[(size_t)sv[it] * 8 + w];
    }
#pragma unroll
    for (int it = 0; it < 8; ++it) {
        vv2[it] = make_float4(0.f, 0.f, 0.f, 0.f);
        if (sv[it] + 1 < ev[it]) vv2[it] = pay4[(size_t)(sv[it] + 1) * 8 + w];
    }
#pragma unroll
    for (int it = 0; it < 8; ++it) {
        float4 acc = make_float4(vv[it].x + vv2[it].x, vv[it].y + vv2[it].y,
                                 vv[it].z + vv2[it].z, vv[it].w + vv2[it].w);
        for (int p = sv[it] + 2; p < ev[it]; ++p) {   // rare tail (8% of cells)
            float4 v2 = pay4[(size_t)p * 8 + w];
            acc.x += v2.x; acc.y += v2.y; acc.z += v2.z; acc.w += v2.w;
        }
        int col = l + (it << 6);
        int bc = (int)(__brev((unsigned)col) >> (32 - LOG2N));   // bit-reversed col
        lds[w][SK(bc)] = acc;
    }
    asm volatile("s_waitcnt lgkmcnt(0)" ::: "memory");

    fft512_wave(&lds[w][0], l);

    // ---- store this wave's 2 channels, coalesced (512-B contiguous per wave) ----
    int c0 = w * 2;
    float2* g0 = grid + (size_t)c0 * NN + (size_t)r * N;
    float2* g1 = grid + (size_t)(c0 + 1) * NN + (size_t)r * N;
    for (int i = l; i < N; i += 64) {
        float4 v = lds[w][SK(i)];
        g0[i] = make_float2(v.x, v.y);
        g1[i] = make_float2(v.z, v.w);
    }
}

// ============ column FFT: full-granule load/store phases (round-12 proven) ============
// I/O phases remap thread t -> (row=t>>3, colpair=t&7): 8 consecutive lanes
// cover one row's 128-B granule on BOTH load and store. Scatter/gather is
// cross-wave -> exactly 2 __syncthreads(); FFT stages stay wave-local.
__global__ __launch_bounds__(512) void colfft_kernel(float2* __restrict__ grid) {
    __shared__ float4 lds[8][LROW];   // 69.8 KB
    int blk = blockIdx.x;             // c * 32 + cg
    int c = blk >> 5;
    int cg = blk & 31;
    int t = threadIdx.x;
    int w = t >> 6;
    int l = t & 63;
    float2* gb = grid + (size_t)c * NN + cg * 16;
    int cp = t & 7;                   // column pair 0..7 within the 16-col slab
    int r0 = t >> 3;                  // base row 0..63

    // ---- load: 8 lanes per row = full 128-B granule; bit-reversed scatter ----
#pragma unroll
    for (int j = 0; j < 8; ++j) {
        int row = r0 + (j << 6);
        float4 v = ((const float4*)(gb + (size_t)row * N))[cp];
        int br = (int)(__brev((unsigned)row) >> (32 - LOG2N));
        lds[cp][SK(br)] = v;
    }
    __syncthreads();

    fft512_wave(&lds[w][0], l);
    __syncthreads();

    // ---- store: natural order, full granules ----
#pragma unroll
    for (int j = 0; j < 8; ++j) {
        int row = r0 + (j << 6);
        ((float4*)(gb + (size_t)row * N))[cp] = lds[cp][SK(row)];
    }
}

// ============ combine: 2 pixels/thread, float4/float2 loads (round-12 proven) ============
__global__ __launch_bounds__(256) void combine_kernel(const float* __restrict__ csr,
                                                      const float* __restrict__ csi,
                                                      const float2* __restrict__ grid,
                                                      float* __restrict__ out) {
    int p2 = blockIdx.x * 256 + threadIdx.x;     // pixel pair index
    int pix = p2 * 2;
    int ny = pix >> LOG2N, nx = pix & (N - 1);
    float ar0 = 0.f, ai0 = 0.f, ar1 = 0.f, ai1 = 0.f;
#pragma unroll
    for (int c = 0; c < C; ++c) {
        float4 uv = ((const float4*)(grid + (size_t)c * NN))[p2];   // 2 complex
        float2 a = ((const float2*)(csr + (size_t)c * NN))[p2];
        float2 b = ((const float2*)(csi + (size_t)c * NN))[p2];
        ar0 += a.x * uv.x + b.x * uv.y;
        ai0 += a.x * uv.y - b.x * uv.x;
        ar1 += a.y * uv.z + b.y * uv.w;
        ai1 += a.y * uv.w - b.y * uv.z;
    }
    float s0 = ((ny + nx) & 1) ? -1.f : 1.f;     // fftshift sign; pair col flips it
    float s1 = -s0;
    ((float2*)out)[p2] = make_float2(s0 * ar0, s1 * ar1);
    ((float2*)(out + NN))[p2] = make_float2(s0 * ai0, s1 * ai1);
}

extern "C" void kernel_launch(void* const* d_in, const int* in_sizes, int n_in,
                              void* d_out, int out_size, void* d_ws, size_t ws_size,
                              hipStream_t stream) {
    const float* x_real   = (const float*)d_in[0];
    const float* x_imag   = (const float*)d_in[1];
    const float* csm_real = (const float*)d_in[2];
    const float* csm_imag = (const float*)d_in[3];
    const float2* traj    = (const float2*)d_in[4];
    const float* dcf      = (const float*)d_in[5];
    float* out = (float*)d_out;

    char* ws = (char*)d_ws;
    size_t o = 0;
    float* grid  = (float*)(ws + o); o += (size_t)C * NN * 2 * sizeof(float);  // 32 MB
    int*   count = (int*)(ws + o);   o += (size_t)NN * sizeof(int);            // 1 MB
    int*   offs  = (int*)(ws + o);   o += ((size_t)NN + 4) * sizeof(int);      // 1 MB (+pad)
    int*   cursor= (int*)(ws + o);   o += (size_t)NN * sizeof(int);            // 1 MB
    float2* pay  = (float2*)(ws + o); o += (size_t)K * 16 * sizeof(float2);    // 32 MB

    (void)hipMemsetAsync(count, 0, (size_t)NN * sizeof(int), stream);

    prep_hist_kernel<<<K / 512, 256, 0, stream>>>((const float4*)traj, count);
    scan_kernel<<<256, 256, 0, stream>>>(count, offs, cursor);
    payload_kernel<<<K / 256, 256, 0, stream>>>(x_real, x_imag, traj, dcf, cursor, pay);
    build8_kernel<<<N, 512, 0, stream>>>(offs, (const float4*)pay, (float2*)grid);
    colfft_kernel<<<C * 32, 512, 0, stream>>>((float2*)grid);
    combine_kernel<<<NN / 512, 256, 0, stream>>>(csm_real, csm_imag, (float2*)grid, out);
}